// Round 6
// baseline (241.854 us; speedup 1.0000x reference)
//
#include <hip/hip_runtime.h>

namespace {

typedef _Float16 half_t;
typedef _Float16 half2_t __attribute__((ext_vector_type(2)));
typedef _Float16 half4_t __attribute__((ext_vector_type(4)));

constexpr int Wd = 160, Hd = 192, Dd = 160;
constexpr int TX = 16, TY = 16, CZ = 40;
constexpr int HW = Hd * Wd;
constexpr int LIVE = CZ + 8;               // 48 slices per block
constexpr float INV_K = 1.0f / 729.0f;
constexpr float INV_TOT = 1.0f / 9830400.0f;   // 2*160*192*160
constexpr int R4 = 17;     // xs4h row stride in half4 units (16 cols + 1 pad)
constexpr int RTH = 68;    // xsTh row stride in half units (x at 4*x)
constexpr int ROWS = 26;   // 24 halo rows + 2 pad rows absorbing lanes 240..255

// ROUND 16 (= R15 resubmitted; R15's bench died on container acquisition,
// not on the kernel): register z-ring with an OPEN register budget.
// R10-R14 post-mortem: the allocator's VGPR target tracks ~2x the
// waves-per-eu argument ((256,4)->64 regs, (256,3)->84, plain/(256,2)->128
// budget). R11/R12's spills (WRITE_SIZE 300-577 MB) were caused by the
// budget being below the ~115-reg demand of {A/B float4 pipeline sets (64)
// + ring (~23) + temporaries}, NOT by the ring-in-registers idea itself.
// This round: (256,1) -> budget 256+, expected use ~120-128 -> 4 waves/SIMD
// by the VGPR occupancy rule, and LDS drops 37.4 -> 14.3 KB (ring leaves
// LDS). 4 blocks/CU resident vs R10's measured 2: doubles the independent
// barrier groups hiding the per-slice latency (R10: all pipes <=50%).
// T-ring packed into half2 pairs (literal slots -> stays in registers).
// INVARIANT to check: WRITE_SIZE ~30 KB. If MB-scale, this line is dead.

__global__ __launch_bounds__(256, 1)
void ncc_main(const float* __restrict__ inp, const float* __restrict__ tgt,
              float* __restrict__ out)
{
    __shared__ half4_t xs4h[2][ROWS * R4];   // 2 x 3536 B
    __shared__ half_t  xsTh[2][ROWS * RTH];  // 2 x 3536 B
    __shared__ float   red[4];

    const int tid = threadIdx.x;
    const int n  = (int)blockIdx.z >> 2;
    const int zc = (int)blockIdx.z & 3;
    const int x0 = blockIdx.x * TX, y0 = blockIdx.y * TY, z0 = zc * CZ;

    // ---- phase-1 decode: (row r 0..25) x (half h) x (field f)
    const int f = tid % 5;
    const int j = tid / 5;
    const int r = j >> 1, h = j & 1;
    const int gy = y0 - 4 + r;
    const bool yok = (tid < 240) && (gy >= 0) && (gy < Hd);
    const int gyc = min(max(gy, 0), Hd - 1);
    const int gxb = x0 - 4 + 8 * h;
    const bool uI = (f == 0) || (f == 1) || (f == 3);
    const float bI = (f == 0) ? 1.f : 0.f;
    const float bT = (f == 1 || f == 2) ? 0.5f : 0.f;
    const float bC = (f == 1 || f == 2) ? 0.5f : ((f >= 3) ? 1.f : 0.f);

#define DECODE(c) \
    int voff##c; float aI##c, aTC##c; \
    { const int gx = gxb + 4 * c; \
      const float m = (yok && gx >= 0 && gx < Wd) ? 1.f : 0.f; \
      const int gxc = min(max(gx, 0), Wd - 4); \
      voff##c = gyc * Wd + gxc; \
      aI##c = uI ? m : 0.f; aTC##c = uI ? 0.f : 0.5f * m; }
    DECODE(0) DECODE(1) DECODE(2) DECODE(3)
#undef DECODE

    const int nb = n * (Dd * HW);            // < 2^24, int math is exact
    const float* baseI = inp + nb;           // uniform -> SGPR pair
    const float* baseT = tgt + nb;

    // unified store base (both layouts are stride-4 halves): static imm offsets
    const int stoff = (f < 4) ? ((r * R4) * 4 + 32 * h + f) : (r * RTH + 32 * h);
    half_t* const st0 = (f < 4) ? ((half_t*)xs4h[0] + stoff) : (xsTh[0] + stoff);
    half_t* const st1 = (f < 4) ? ((half_t*)xs4h[1] + stoff) : (xsTh[1] + stoff);

    // ---- phase-2 decode: one output column (yi, xi)
    const int yi = tid >> 4, xi = tid & 15;
    const half4_t* const rd4_0 = &xs4h[0][yi * R4 + xi];
    const half4_t* const rd4_1 = &xs4h[1][yi * R4 + xi];
    const half_t*  const rdT_0 = &xsTh[0][yi * RTH + 4 * xi];
    const half_t*  const rdT_1 = &xsTh[1][yi * RTH + 4 * xi];

    float4 S4 = make_float4(0.f, 0.f, 0.f, 0.f);
    float ST = 0.f, acc = 0.f;

    // z-ring in registers: slot index is a literal token in every access.
    // AB ring: 9 x (half2 + half2) = 18 VGPRs; T ring packed: 5 half2 = 5.
    half2_t rg01[9], rg23[9];
    half2_t rgT2[5];
    #pragma unroll
    for (int q = 0; q < 9; ++q) { rg01[q] = (half2_t)0; rg23[q] = (half2_t)0; }
    #pragma unroll
    for (int q = 0; q < 5; ++q) { rgT2[q] = (half2_t)0; }

    // two prefetch sets, roles alternate with static slice parity
#define DECL_SET(S) \
    float4 S##I0, S##I1, S##I2, S##I3, S##T0, S##T1, S##T2, S##T3; \
    S##I0 = S##I1 = S##I2 = S##I3 = make_float4(0.f, 0.f, 0.f, 0.f); \
    S##T0 = S##T1 = S##T2 = S##T3 = S##I0;
    DECL_SET(A) DECL_SET(B)
#undef DECL_SET

#define PRELOAD(S, zz) { \
    const float* pI = baseI + (zz) * HW; \
    const float* pT = baseT + (zz) * HW; \
    S##I0 = *(const float4*)(pI + voff0); S##T0 = *(const float4*)(pT + voff0); \
    S##I1 = *(const float4*)(pI + voff1); S##T1 = *(const float4*)(pT + voff1); \
    S##I2 = *(const float4*)(pI + voff2); S##T2 = *(const float4*)(pT + voff2); \
    S##I3 = *(const float4*)(pI + voff3); S##T3 = *(const float4*)(pT + voff3); }

    // prologue: s=0 -> set A (even), s=1 -> set B (odd)
    if (z0 - 4 >= 0) PRELOAD(A, z0 - 4)
    if (z0 - 3 >= 0) PRELOAD(B, z0 - 3)

#define PRODC(S, c, P0, P1, P2, P3) { \
    P0 = fmaf(S##I##c.x, aI##c, fmaf(S##T##c.x, aTC##c, aTC##c)) * fmaf(S##I##c.x, bI, fmaf(S##T##c.x, bT, bC)); \
    P1 = fmaf(S##I##c.y, aI##c, fmaf(S##T##c.y, aTC##c, aTC##c)) * fmaf(S##I##c.y, bI, fmaf(S##T##c.y, bT, bC)); \
    P2 = fmaf(S##I##c.z, aI##c, fmaf(S##T##c.z, aTC##c, aTC##c)) * fmaf(S##I##c.z, bI, fmaf(S##T##c.z, bT, bC)); \
    P3 = fmaf(S##I##c.w, aI##c, fmaf(S##T##c.w, aTC##c, aTC##c)) * fmaf(S##I##c.w, bI, fmaf(S##T##c.w, bT, bC)); }

    // body for one slice; SET = prefetch set holding slice s (also target of
    // the s+2 load, same parity); U = literal step 0..17; SL = literal U%9
#define SLICE_BODY(SET, U, SL) { \
    const int s = tb + (U); \
    const int zi = z0 - 4 + s; \
    const bool zok = (zi >= 0) && (zi < Dd);        /* uniform */ \
    float o0, o1, o2, o3, o4, o5, o6, o7; \
    if (zok) { \
        float p0, p1, p2, p3, p4, p5, p6, p7; \
        float p8, p9, p10, p11, p12, p13, p14, p15; \
        PRODC(SET, 0, p0,  p1,  p2,  p3) \
        PRODC(SET, 1, p4,  p5,  p6,  p7) \
        PRODC(SET, 2, p8,  p9,  p10, p11) \
        PRODC(SET, 3, p12, p13, p14, p15) \
        float ss = p0 + p1 + p2 + p3 + p4 + p5 + p6 + p7 + p8; \
        o0 = ss; \
        ss += p9  - p0; o1 = ss; \
        ss += p10 - p1; o2 = ss; \
        ss += p11 - p2; o3 = ss; \
        ss += p12 - p3; o4 = ss; \
        ss += p13 - p4; o5 = ss; \
        ss += p14 - p5; o6 = ss; \
        ss += p15 - p6; o7 = ss; \
    } \
    {   /* prefetch slice s+2 into the same set (depth-2 pipeline) */ \
        const int zi2 = z0 - 2 + s; \
        if ((s + 2) < LIVE && zi2 >= 0 && zi2 < Dd) PRELOAD(SET, zi2) \
    } \
    if (zok) { \
        half_t* const st = ((U) & 1) ? st1 : st0; \
        st[0]  = (half_t)o0; st[4]  = (half_t)o1; \
        st[8]  = (half_t)o2; st[12] = (half_t)o3; \
        st[16] = (half_t)o4; st[20] = (half_t)o5; \
        st[24] = (half_t)o6; st[28] = (half_t)o7; \
    } \
    __syncthreads();                                /* single barrier */ \
    half2_t a01 = (half2_t)0, a23 = (half2_t)0; \
    half_t aT = (half_t)0.f; \
    if (zok) { \
        const half4_t* const rd4 = ((U) & 1) ? rd4_1 : rd4_0; \
        const half_t*  const rdT = ((U) & 1) ? rdT_1 : rdT_0; \
        _Pragma("unroll") \
        for (int k = 0; k < 9; ++k) { \
            const half4_t v = rd4[k * R4]; \
            const half2_t vlo = {v.x, v.y}; \
            const half2_t vhi = {v.z, v.w}; \
            a01 += vlo; a23 += vhi; \
            aT += rdT[k * RTH]; \
        } \
    } \
    {   /* register z-ring (static literal slot, thread-private) */ \
        const half2_t o01 = rg01[SL]; \
        const half2_t o23 = rg23[SL]; \
        const half_t  oT  = rgT2[(SL) >> 1][(SL) & 1]; \
        S4.x += (float)a01.x - (float)o01.x; \
        S4.y += (float)a01.y - (float)o01.y; \
        S4.z += (float)a23.x - (float)o23.x; \
        S4.w += (float)a23.y - (float)o23.y; \
        ST   += (float)aT - (float)oT; \
        rg01[SL] = a01; rg23[SL] = a23; \
        rgT2[(SL) >> 1][(SL) & 1] = aT; \
    } \
    if (s >= 8) {                                   /* output z = z0+s-8 */ \
        const float sii = S4.x, sit = S4.y, stt = S4.z, si = S4.w, stv = ST; \
        const float cross = sit - si * stv * INV_K; \
        const float tvar  = stt - stv * stv * INV_K; \
        const float ivar  = sii - si  * si  * INV_K; \
        acc += cross * cross * __builtin_amdgcn_rcpf(tvar * ivar + 1e-5f); \
    } }

#define STEP(U, SL, SET) if (tb + (U) < LIVE) SLICE_BODY(SET, U, SL)

    for (int tb = 0; tb < 54; tb += 18) {          // 48 live; 18-step expansion
        STEP(0, 0, A)  STEP(1, 1, B)  STEP(2, 2, A)  STEP(3, 3, B)
        STEP(4, 4, A)  STEP(5, 5, B)  STEP(6, 6, A)  STEP(7, 7, B)
        STEP(8, 8, A)  STEP(9, 0, B)  STEP(10, 1, A) STEP(11, 2, B)
        STEP(12, 3, A) STEP(13, 4, B) STEP(14, 5, A) STEP(15, 6, B)
        STEP(16, 7, A) STEP(17, 8, B)
    }
#undef STEP
#undef SLICE_BODY
#undef PRELOAD
#undef PRODC

    // ---- block reduction + fused finalize (one atomic per block)
    #pragma unroll
    for (int off = 32; off > 0; off >>= 1) acc += __shfl_down(acc, off, 64);
    if ((tid & 63) == 0) red[tid >> 6] = acc;
    __syncthreads();
    if (tid == 0) {
        const float tot = red[0] + red[1] + red[2] + red[3];
        atomicAdd(out, -tot * INV_TOT);
    }
}

} // namespace

extern "C" void kernel_launch(void* const* d_in, const int* in_sizes, int n_in,
                              void* d_out, int out_size, void* d_ws, size_t ws_size,
                              hipStream_t stream)
{
    const float* inp = (const float*)d_in[0];
    const float* tgt = (const float*)d_in[1];
    float* out = (float*)d_out;

    hipMemsetAsync(d_out, 0, sizeof(float), stream);   // d_out re-poisoned each call
    dim3 grid(Wd / TX, Hd / TY, 2 * (Dd / CZ));        // (10,12,8) = 960 blocks
    ncc_main<<<grid, 256, 0, stream>>>(inp, tgt, out);
}

// Round 7
// 169.237 us; speedup vs baseline: 1.4291x; 1.4291x over previous
//
#include <hip/hip_runtime.h>

namespace {

typedef _Float16 half_t;
typedef _Float16 half2_t __attribute__((ext_vector_type(2)));
typedef _Float16 half4_t __attribute__((ext_vector_type(4)));

constexpr int Wd = 160, Hd = 192, Dd = 160;
constexpr int TX = 16, TY = 16, CZ = 40;
constexpr int HW = Hd * Wd;
constexpr int LIVE = CZ + 8;               // 48 slices per block
constexpr float INV_K = 1.0f / 729.0f;
constexpr float INV_TOT = 1.0f / 9830400.0f;   // 2*160*192*160
constexpr int R4 = 17;     // xs4h row stride in half4 units (16 cols + 1 pad)
constexpr int RTH = 68;    // xsTh row stride in half units (x at 4*x)
constexpr int ROWS = 26;   // 24 halo rows + 2 pad rows absorbing lanes 240..255

// ROUND 17: XCD-aware block swizzle on the R10/R14 base.
// R10-R16 post-mortem: VGPR allocation has a coarse HW quantum {64,128,256}
// over a 512-reg/SIMD pool (m69). R10 (84 regs -> 128 quantum) is ALREADY
// at the 4 waves/SIMD ceiling = 4 blocks/CU; R16 (152 regs -> 256 quantum)
// halved that and doubled time. Occupancy cannot go higher with >=84-reg
// demand -- that program is closed. The remaining diagnosis: latency-bound
// on L2 MISSES. FETCH 210 MB == full halo-implied over-fetch (2.25x xy *
// 1.2x z * 78.6 MB), so halo re-reads are NOT hitting L2: x/y-neighbor
// blocks land on different XCDs under default round-robin dispatch.
// Fix: 960 blocks = 8 XCDs x 120; remap so each XCD-class owns one full
// x-y plane (one (n,zc) chunk, working set ~1.5 MB < 4 MB L2). xy-halo
// re-reads become same-XCD L2 hits (~200 cyc vs ~600-900).
// Predicted: FETCH 210 -> ~95-130 MB, dur 94.5 -> ~70-80 us.

__global__ __launch_bounds__(256)
void ncc_main(const float* __restrict__ inp, const float* __restrict__ tgt,
              float* __restrict__ out)
{
    __shared__ half4_t xs4h[2][ROWS * R4];   // 2 x 3536 B
    __shared__ half_t  xsTh[2][ROWS * RTH];  // 2 x 3536 B
    __shared__ half4_t ringAB[9 * 256];      // 18432 B: z-ring {II,IT,TT,I}
    __shared__ half_t  ringT[9 * 256];       //  4608 B: z-ring {T}
    __shared__ float   red[4];

    const int tid = threadIdx.x;

    // ---- XCD-aware remap: linear id -> (xcd p = lin%8) owns plane bz = p.
    // 960 = 8*120 exactly -> bijective. Within a plane, q = lin/8 walks the
    // 10x12 x-y grid, so L2-sharing neighbors are co-resident on one XCD.
    const int lin = (int)blockIdx.x + 10 * (int)blockIdx.y + 120 * (int)blockIdx.z;
    const int swz = (lin & 7) * 120 + (lin >> 3);
    const int bx = swz % 10;
    const int by = (swz / 10) % 12;
    const int bz = swz / 120;

    const int n  = bz >> 2;
    const int zc = bz & 3;
    const int x0 = bx * TX, y0 = by * TY, z0 = zc * CZ;

    // zero the ring (thread-private slots; no sync needed)
    #pragma unroll
    for (int q = 0; q < 9; ++q) {
        ringAB[q * 256 + tid] = (half4_t)0;
        ringT[q * 256 + tid] = (half_t)0.f;
    }

    // ---- phase-1 decode: (row r 0..25) x (half h) x (field f)
    const int f = tid % 5;
    const int j = tid / 5;
    const int r = j >> 1, h = j & 1;
    const int gy = y0 - 4 + r;
    const bool yok = (tid < 240) && (gy >= 0) && (gy < Hd);
    const int gyc = min(max(gy, 0), Hd - 1);
    const int gxb = x0 - 4 + 8 * h;
    const bool uI = (f == 0) || (f == 1) || (f == 3);
    const float bI = (f == 0) ? 1.f : 0.f;
    const float bT = (f == 1 || f == 2) ? 0.5f : 0.f;
    const float bC = (f == 1 || f == 2) ? 0.5f : ((f >= 3) ? 1.f : 0.f);

#define DECODE(c) \
    int voff##c; float aI##c, aTC##c; \
    { const int gx = gxb + 4 * c; \
      const float m = (yok && gx >= 0 && gx < Wd) ? 1.f : 0.f; \
      const int gxc = min(max(gx, 0), Wd - 4); \
      voff##c = gyc * Wd + gxc; \
      aI##c = uI ? m : 0.f; aTC##c = uI ? 0.f : 0.5f * m; }
    DECODE(0) DECODE(1) DECODE(2) DECODE(3)
#undef DECODE

    const int nb = n * (Dd * HW);            // < 2^24, int math is exact
    const float* baseI = inp + nb;           // uniform -> SGPR pair
    const float* baseT = tgt + nb;

    // unified store base (both layouts are stride-4 halves): static imm offsets
    const int stoff = (f < 4) ? ((r * R4) * 4 + 32 * h + f) : (r * RTH + 32 * h);
    half_t* const st0 = (f < 4) ? ((half_t*)xs4h[0] + stoff) : (xsTh[0] + stoff);
    half_t* const st1 = (f < 4) ? ((half_t*)xs4h[1] + stoff) : (xsTh[1] + stoff);

    // ---- phase-2 decode: one output column (yi, xi)
    const int yi = tid >> 4, xi = tid & 15;
    const half4_t* const rd4_0 = &xs4h[0][yi * R4 + xi];
    const half4_t* const rd4_1 = &xs4h[1][yi * R4 + xi];
    const half_t*  const rdT_0 = &xsTh[0][yi * RTH + 4 * xi];
    const half_t*  const rdT_1 = &xsTh[1][yi * RTH + 4 * xi];

    float4 S4 = make_float4(0.f, 0.f, 0.f, 0.f);
    float ST = 0.f, acc = 0.f;

    // two prefetch sets, roles alternate with static slice parity
#define DECL_SET(S) \
    float4 S##I0, S##I1, S##I2, S##I3, S##T0, S##T1, S##T2, S##T3; \
    S##I0 = S##I1 = S##I2 = S##I3 = make_float4(0.f, 0.f, 0.f, 0.f); \
    S##T0 = S##T1 = S##T2 = S##T3 = S##I0;
    DECL_SET(A) DECL_SET(B)
#undef DECL_SET

#define PRELOAD(S, zz) { \
    const float* pI = baseI + (zz) * HW; \
    const float* pT = baseT + (zz) * HW; \
    S##I0 = *(const float4*)(pI + voff0); S##T0 = *(const float4*)(pT + voff0); \
    S##I1 = *(const float4*)(pI + voff1); S##T1 = *(const float4*)(pT + voff1); \
    S##I2 = *(const float4*)(pI + voff2); S##T2 = *(const float4*)(pT + voff2); \
    S##I3 = *(const float4*)(pI + voff3); S##T3 = *(const float4*)(pT + voff3); }

    // prologue: s=0 -> set A (even), s=1 -> set B (odd)
    if (z0 - 4 >= 0) PRELOAD(A, z0 - 4)
    if (z0 - 3 >= 0) PRELOAD(B, z0 - 3)

#define PRODC(S, c, P0, P1, P2, P3) { \
    P0 = fmaf(S##I##c.x, aI##c, fmaf(S##T##c.x, aTC##c, aTC##c)) * fmaf(S##I##c.x, bI, fmaf(S##T##c.x, bT, bC)); \
    P1 = fmaf(S##I##c.y, aI##c, fmaf(S##T##c.y, aTC##c, aTC##c)) * fmaf(S##I##c.y, bI, fmaf(S##T##c.y, bT, bC)); \
    P2 = fmaf(S##I##c.z, aI##c, fmaf(S##T##c.z, aTC##c, aTC##c)) * fmaf(S##I##c.z, bI, fmaf(S##T##c.z, bT, bC)); \
    P3 = fmaf(S##I##c.w, aI##c, fmaf(S##T##c.w, aTC##c, aTC##c)) * fmaf(S##I##c.w, bI, fmaf(S##T##c.w, bT, bC)); }

    // body for one slice; SET = prefetch set holding slice s, also the
    // target for the s+2 load (same parity)
#define SLICE_BODY(SET) { \
    const int zi = z0 - 4 + s; \
    const bool zok = (zi >= 0) && (zi < Dd);        /* uniform */ \
    const int sl = u % 9;                           /* static */ \
    const int pb = u & 1;                           /* static */ \
    float o0, o1, o2, o3, o4, o5, o6, o7; \
    if (zok) { \
        float p0, p1, p2, p3, p4, p5, p6, p7; \
        float p8, p9, p10, p11, p12, p13, p14, p15; \
        PRODC(SET, 0, p0,  p1,  p2,  p3) \
        PRODC(SET, 1, p4,  p5,  p6,  p7) \
        PRODC(SET, 2, p8,  p9,  p10, p11) \
        PRODC(SET, 3, p12, p13, p14, p15) \
        float ss = p0 + p1 + p2 + p3 + p4 + p5 + p6 + p7 + p8; \
        o0 = ss; \
        ss += p9  - p0; o1 = ss; \
        ss += p10 - p1; o2 = ss; \
        ss += p11 - p2; o3 = ss; \
        ss += p12 - p3; o4 = ss; \
        ss += p13 - p4; o5 = ss; \
        ss += p14 - p5; o6 = ss; \
        ss += p15 - p6; o7 = ss; \
    } \
    {   /* prefetch slice s+2 into the same set (depth-2 pipeline) */ \
        const int zi2 = z0 - 2 + s; \
        if ((s + 2) < LIVE && zi2 >= 0 && zi2 < Dd) PRELOAD(SET, zi2) \
    } \
    if (zok) { \
        half_t* const st = pb ? st1 : st0; \
        st[0]  = (half_t)o0; st[4]  = (half_t)o1; \
        st[8]  = (half_t)o2; st[12] = (half_t)o3; \
        st[16] = (half_t)o4; st[20] = (half_t)o5; \
        st[24] = (half_t)o6; st[28] = (half_t)o7; \
    } \
    __syncthreads();                                /* single barrier */ \
    half2_t a01 = (half2_t)0, a23 = (half2_t)0; \
    half_t aT = (half_t)0.f; \
    if (zok) { \
        const half4_t* const rd4 = pb ? rd4_1 : rd4_0; \
        const half_t*  const rdT = pb ? rdT_1 : rdT_0; \
        _Pragma("unroll") \
        for (int k = 0; k < 9; ++k) { \
            const half4_t v = rd4[k * R4]; \
            const half2_t vlo = {v.x, v.y}; \
            const half2_t vhi = {v.z, v.w}; \
            a01 += vlo; a23 += vhi; \
            aT += rdT[k * RTH]; \
        } \
    } \
    {   /* LDS z-ring (thread-private, static slot offsets, no sync) */ \
        const half4_t oAB = ringAB[sl * 256 + tid]; \
        const half_t  oT  = ringT[sl * 256 + tid]; \
        S4.x += (float)a01.x - (float)oAB.x; \
        S4.y += (float)a01.y - (float)oAB.y; \
        S4.z += (float)a23.x - (float)oAB.z; \
        S4.w += (float)a23.y - (float)oAB.w; \
        ST   += (float)aT - (float)oT; \
        const half4_t nAB = {a01.x, a01.y, a23.x, a23.y}; \
        ringAB[sl * 256 + tid] = nAB; \
        ringT[sl * 256 + tid]  = aT; \
    } \
    if (s >= 8) {                                   /* output z = z0+s-8 */ \
        const float sii = S4.x, sit = S4.y, stt = S4.z, si = S4.w, stv = ST; \
        const float cross = sit - si * stv * INV_K; \
        const float tvar  = stt - stv * stv * INV_K; \
        const float ivar  = sii - si  * si  * INV_K; \
        acc += cross * cross * __builtin_amdgcn_rcpf(tvar * ivar + 1e-5f); \
    } }

    for (int tb = 0; tb < 54; tb += 18) {          // 48 live; 18-unroll
        #pragma unroll
        for (int u = 0; u < 18; ++u) {
            const int s = tb + u;                  // block-uniform
            if (s < LIVE) {
                if ((u & 1) == 0) SLICE_BODY(A)
                else              SLICE_BODY(B)
            }
        }
    }
#undef SLICE_BODY
#undef PRELOAD
#undef PRODC

    // ---- block reduction + fused finalize (one atomic per block)
    #pragma unroll
    for (int off = 32; off > 0; off >>= 1) acc += __shfl_down(acc, off, 64);
    if ((tid & 63) == 0) red[tid >> 6] = acc;
    __syncthreads();
    if (tid == 0) {
        const float tot = red[0] + red[1] + red[2] + red[3];
        atomicAdd(out, -tot * INV_TOT);
    }
}

} // namespace

extern "C" void kernel_launch(void* const* d_in, const int* in_sizes, int n_in,
                              void* d_out, int out_size, void* d_ws, size_t ws_size,
                              hipStream_t stream)
{
    const float* inp = (const float*)d_in[0];
    const float* tgt = (const float*)d_in[1];
    float* out = (float*)d_out;

    hipMemsetAsync(d_out, 0, sizeof(float), stream);   // d_out re-poisoned each call
    dim3 grid(Wd / TX, Hd / TY, 2 * (Dd / CZ));        // (10,12,8) = 960 blocks
    ncc_main<<<grid, 256, 0, stream>>>(inp, tgt, out);
}

// Round 8
// 166.103 us; speedup vs baseline: 1.4560x; 1.0189x over previous
//
#include <hip/hip_runtime.h>

namespace {

typedef _Float16 half_t;
typedef _Float16 half2_t __attribute__((ext_vector_type(2)));
typedef _Float16 half4_t __attribute__((ext_vector_type(4)));

constexpr int Wd = 160, Hd = 192, Dd = 160;
constexpr int TX = 16, TY = 16, CZ = 40;
constexpr int HW = Hd * Wd;
constexpr int LIVE = CZ + 8;               // 48 slices per block
constexpr float INV_K = 1.0f / 729.0f;
constexpr float INV_TOT = 1.0f / 9830400.0f;   // 2*160*192*160
constexpr int R4 = 17;     // xs4h row stride in half4 units (16 cols + 1 pad)
constexpr int RTH = 68;    // xsTh row stride in half units (x at 4*x)
constexpr int ROWS = 26;   // 24 halo rows + 2 pad rows absorbing lanes 240..255

// ROUND 18: paired-output y-sum (2 outputs/thread in phase-2).
// R17 proved memory is off the critical path: swizzle cut FETCH 210->46 MB
// yet dur unchanged (96.5 vs 94.5 us) -- the kernel is bound by on-CU work:
// LDS pipe ~65% (30 instrs/wave-slice, dominated by 9x row re-read overlap
// in the y-window sum), VALU 45%. This round: phase-2 threads t<128 own
// output pair (xi, 2yp) & (xi, 2yp+1): read rows 2yp..2yp+9 ONCE (10 rows),
// shared mid-sum rows 1..8, sum0=mid+row0, sum1=mid+row9. Per-output row
// reads 9 -> 5; ring entries pair-adjacent (b64/b128-mergeable, half the
// wave-instrs); stores/phase-1/swizzle unchanged. Waves 2-3 flow into next
// slice's phase-1 after the barrier (parity buffers allow it).
// INVARIANTS: VGPR < 128 (quantum cliff), WRITE_SIZE ~30 KB (no spill).

__global__ __launch_bounds__(256)
void ncc_main(const float* __restrict__ inp, const float* __restrict__ tgt,
              float* __restrict__ out)
{
    __shared__ half4_t xs4h[2][ROWS * R4];   // 2 x 3536 B
    __shared__ half_t  xsTh[2][ROWS * RTH];  // 2 x 3536 B
    __shared__ half4_t ringAB[9 * 256];      // 18432 B: z-ring {II,IT,TT,I}
    __shared__ half_t  ringT[9 * 256];       //  4608 B: z-ring {T}
    __shared__ float   red[4];

    const int tid = threadIdx.x;

    // ---- XCD-aware remap (kept from R17: FETCH 210->46 MB).
    const int lin = (int)blockIdx.x + 10 * (int)blockIdx.y + 120 * (int)blockIdx.z;
    const int swz = (lin & 7) * 120 + (lin >> 3);
    const int bx = swz % 10;
    const int by = (swz / 10) % 12;
    const int bz = swz / 120;

    const int n  = bz >> 2;
    const int zc = bz & 3;
    const int x0 = bx * TX, y0 = by * TY, z0 = zc * CZ;

    // zero the ring (covers all 256 entries per slot; no sync needed)
    #pragma unroll
    for (int q = 0; q < 9; ++q) {
        ringAB[q * 256 + tid] = (half4_t)0;
        ringT[q * 256 + tid] = (half_t)0.f;
    }

    // ---- phase-1 decode: (row r 0..25) x (half h) x (field f)
    const int f = tid % 5;
    const int j = tid / 5;
    const int r = j >> 1, h = j & 1;
    const int gy = y0 - 4 + r;
    const bool yok = (tid < 240) && (gy >= 0) && (gy < Hd);
    const int gyc = min(max(gy, 0), Hd - 1);
    const int gxb = x0 - 4 + 8 * h;
    const bool uI = (f == 0) || (f == 1) || (f == 3);
    const float bI = (f == 0) ? 1.f : 0.f;
    const float bT = (f == 1 || f == 2) ? 0.5f : 0.f;
    const float bC = (f == 1 || f == 2) ? 0.5f : ((f >= 3) ? 1.f : 0.f);

#define DECODE(c) \
    int voff##c; float aI##c, aTC##c; \
    { const int gx = gxb + 4 * c; \
      const float m = (yok && gx >= 0 && gx < Wd) ? 1.f : 0.f; \
      const int gxc = min(max(gx, 0), Wd - 4); \
      voff##c = gyc * Wd + gxc; \
      aI##c = uI ? m : 0.f; aTC##c = uI ? 0.f : 0.5f * m; }
    DECODE(0) DECODE(1) DECODE(2) DECODE(3)
#undef DECODE

    const int nb = n * (Dd * HW);            // < 2^24, int math is exact
    const float* baseI = inp + nb;           // uniform -> SGPR pair
    const float* baseT = tgt + nb;

    // unified store base (both layouts are stride-4 halves): static imm offsets
    const int stoff = (f < 4) ? ((r * R4) * 4 + 32 * h + f) : (r * RTH + 32 * h);
    half_t* const st0 = (f < 4) ? ((half_t*)xs4h[0] + stoff) : (xsTh[0] + stoff);
    half_t* const st1 = (f < 4) ? ((half_t*)xs4h[1] + stoff) : (xsTh[1] + stoff);

    // ---- phase-2 decode: thread t<128 owns output pair (xi, 2yp),(xi, 2yp+1)
    const int xi = tid & 15;
    const int yp = (tid >> 4) & 7;
    const bool p2on = tid < 128;
    const half4_t* const rd4_0 = &xs4h[0][(2 * yp) * R4 + xi];
    const half4_t* const rd4_1 = &xs4h[1][(2 * yp) * R4 + xi];
    const half_t*  const rdT_0 = &xsTh[0][(2 * yp) * RTH + 4 * xi];
    const half_t*  const rdT_1 = &xsTh[1][(2 * yp) * RTH + 4 * xi];

    float4 S4a = make_float4(0.f, 0.f, 0.f, 0.f);
    float4 S4b = make_float4(0.f, 0.f, 0.f, 0.f);
    float STa = 0.f, STb = 0.f, acc = 0.f;

    // two prefetch sets, roles alternate with static slice parity
#define DECL_SET(S) \
    float4 S##I0, S##I1, S##I2, S##I3, S##T0, S##T1, S##T2, S##T3; \
    S##I0 = S##I1 = S##I2 = S##I3 = make_float4(0.f, 0.f, 0.f, 0.f); \
    S##T0 = S##T1 = S##T2 = S##T3 = S##I0;
    DECL_SET(A) DECL_SET(B)
#undef DECL_SET

#define PRELOAD(S, zz) { \
    const float* pI = baseI + (zz) * HW; \
    const float* pT = baseT + (zz) * HW; \
    S##I0 = *(const float4*)(pI + voff0); S##T0 = *(const float4*)(pT + voff0); \
    S##I1 = *(const float4*)(pI + voff1); S##T1 = *(const float4*)(pT + voff1); \
    S##I2 = *(const float4*)(pI + voff2); S##T2 = *(const float4*)(pT + voff2); \
    S##I3 = *(const float4*)(pI + voff3); S##T3 = *(const float4*)(pT + voff3); }

    // prologue: s=0 -> set A (even), s=1 -> set B (odd)
    if (z0 - 4 >= 0) PRELOAD(A, z0 - 4)
    if (z0 - 3 >= 0) PRELOAD(B, z0 - 3)

#define PRODC(S, c, P0, P1, P2, P3) { \
    P0 = fmaf(S##I##c.x, aI##c, fmaf(S##T##c.x, aTC##c, aTC##c)) * fmaf(S##I##c.x, bI, fmaf(S##T##c.x, bT, bC)); \
    P1 = fmaf(S##I##c.y, aI##c, fmaf(S##T##c.y, aTC##c, aTC##c)) * fmaf(S##I##c.y, bI, fmaf(S##T##c.y, bT, bC)); \
    P2 = fmaf(S##I##c.z, aI##c, fmaf(S##T##c.z, aTC##c, aTC##c)) * fmaf(S##I##c.z, bI, fmaf(S##T##c.z, bT, bC)); \
    P3 = fmaf(S##I##c.w, aI##c, fmaf(S##T##c.w, aTC##c, aTC##c)) * fmaf(S##I##c.w, bI, fmaf(S##T##c.w, bT, bC)); }

    // body for one slice; SET = prefetch set holding slice s, also the
    // target for the s+2 load (same parity)
#define SLICE_BODY(SET) { \
    const int zi = z0 - 4 + s; \
    const bool zok = (zi >= 0) && (zi < Dd);        /* uniform */ \
    const int sl = u % 9;                           /* static */ \
    const int pb = u & 1;                           /* static */ \
    float o0, o1, o2, o3, o4, o5, o6, o7; \
    if (zok) { \
        float p0, p1, p2, p3, p4, p5, p6, p7; \
        float p8, p9, p10, p11, p12, p13, p14, p15; \
        PRODC(SET, 0, p0,  p1,  p2,  p3) \
        PRODC(SET, 1, p4,  p5,  p6,  p7) \
        PRODC(SET, 2, p8,  p9,  p10, p11) \
        PRODC(SET, 3, p12, p13, p14, p15) \
        float ss = p0 + p1 + p2 + p3 + p4 + p5 + p6 + p7 + p8; \
        o0 = ss; \
        ss += p9  - p0; o1 = ss; \
        ss += p10 - p1; o2 = ss; \
        ss += p11 - p2; o3 = ss; \
        ss += p12 - p3; o4 = ss; \
        ss += p13 - p4; o5 = ss; \
        ss += p14 - p5; o6 = ss; \
        ss += p15 - p6; o7 = ss; \
    } \
    {   /* prefetch slice s+2 into the same set (depth-2 pipeline) */ \
        const int zi2 = z0 - 2 + s; \
        if ((s + 2) < LIVE && zi2 >= 0 && zi2 < Dd) PRELOAD(SET, zi2) \
    } \
    if (zok) { \
        half_t* const st = pb ? st1 : st0; \
        st[0]  = (half_t)o0; st[4]  = (half_t)o1; \
        st[8]  = (half_t)o2; st[12] = (half_t)o3; \
        st[16] = (half_t)o4; st[20] = (half_t)o5; \
        st[24] = (half_t)o6; st[28] = (half_t)o7; \
    } \
    __syncthreads();                                /* single barrier */ \
    half2_t a01_0 = (half2_t)0, a23_0 = (half2_t)0; \
    half2_t a01_1 = (half2_t)0, a23_1 = (half2_t)0; \
    half_t aT0 = (half_t)0.f, aT1 = (half_t)0.f; \
    if (zok && p2on) { \
        const half4_t* const rd4 = pb ? rd4_1 : rd4_0; \
        const half_t*  const rdT = pb ? rdT_1 : rdT_0; \
        const half4_t v0 = rd4[0]; \
        const half4_t v9 = rd4[9 * R4]; \
        const half_t t0 = rdT[0]; \
        const half_t t9 = rdT[9 * RTH]; \
        half2_t m01 = (half2_t)0, m23 = (half2_t)0; \
        half_t mT = (half_t)0.f; \
        _Pragma("unroll") \
        for (int k = 1; k < 9; ++k) { \
            const half4_t v = rd4[k * R4]; \
            const half2_t vlo = {v.x, v.y}; \
            const half2_t vhi = {v.z, v.w}; \
            m01 += vlo; m23 += vhi; \
            mT += rdT[k * RTH]; \
        } \
        const half2_t v0lo = {v0.x, v0.y}, v0hi = {v0.z, v0.w}; \
        const half2_t v9lo = {v9.x, v9.y}, v9hi = {v9.z, v9.w}; \
        a01_0 = m01 + v0lo; a23_0 = m23 + v0hi; aT0 = mT + t0; \
        a01_1 = m01 + v9lo; a23_1 = m23 + v9hi; aT1 = mT + t9; \
    } \
    if (p2on) { /* ring shift (zeros when !zok) + accumulate, pair-adjacent */ \
        half4_t* const rAB = &ringAB[sl * 256 + 2 * tid]; \
        half2_t* const rT  = (half2_t*)&ringT[sl * 256 + 2 * tid]; \
        const half4_t oA0 = rAB[0]; \
        const half4_t oA1 = rAB[1]; \
        const half2_t oT  = *rT; \
        S4a.x += (float)a01_0.x - (float)oA0.x; \
        S4a.y += (float)a01_0.y - (float)oA0.y; \
        S4a.z += (float)a23_0.x - (float)oA0.z; \
        S4a.w += (float)a23_0.y - (float)oA0.w; \
        STa   += (float)aT0 - (float)oT.x; \
        S4b.x += (float)a01_1.x - (float)oA1.x; \
        S4b.y += (float)a01_1.y - (float)oA1.y; \
        S4b.z += (float)a23_1.x - (float)oA1.z; \
        S4b.w += (float)a23_1.y - (float)oA1.w; \
        STb   += (float)aT1 - (float)oT.y; \
        const half4_t nA0 = {a01_0.x, a01_0.y, a23_0.x, a23_0.y}; \
        const half4_t nA1 = {a01_1.x, a01_1.y, a23_1.x, a23_1.y}; \
        rAB[0] = nA0; rAB[1] = nA1; \
        const half2_t nT = {aT0, aT1}; \
        *rT = nT; \
    } \
    if (s >= 8 && p2on) {                           /* output z = z0+s-8 */ \
        { const float sii = S4a.x, sit = S4a.y, stt = S4a.z, si = S4a.w, stv = STa; \
          const float cross = sit - si * stv * INV_K; \
          const float tvar  = stt - stv * stv * INV_K; \
          const float ivar  = sii - si  * si  * INV_K; \
          acc += cross * cross * __builtin_amdgcn_rcpf(tvar * ivar + 1e-5f); } \
        { const float sii = S4b.x, sit = S4b.y, stt = S4b.z, si = S4b.w, stv = STb; \
          const float cross = sit - si * stv * INV_K; \
          const float tvar  = stt - stv * stv * INV_K; \
          const float ivar  = sii - si  * si  * INV_K; \
          acc += cross * cross * __builtin_amdgcn_rcpf(tvar * ivar + 1e-5f); } \
    } }

    for (int tb = 0; tb < 54; tb += 18) {          // 48 live; 18-unroll
        #pragma unroll
        for (int u = 0; u < 18; ++u) {
            const int s = tb + u;                  // block-uniform
            if (s < LIVE) {
                if ((u & 1) == 0) SLICE_BODY(A)
                else              SLICE_BODY(B)
            }
        }
    }
#undef SLICE_BODY
#undef PRELOAD
#undef PRODC

    // ---- block reduction + fused finalize (one atomic per block)
    #pragma unroll
    for (int off = 32; off > 0; off >>= 1) acc += __shfl_down(acc, off, 64);
    if ((tid & 63) == 0) red[tid >> 6] = acc;
    __syncthreads();
    if (tid == 0) {
        const float tot = red[0] + red[1] + red[2] + red[3];
        atomicAdd(out, -tot * INV_TOT);
    }
}

} // namespace

extern "C" void kernel_launch(void* const* d_in, const int* in_sizes, int n_in,
                              void* d_out, int out_size, void* d_ws, size_t ws_size,
                              hipStream_t stream)
{
    const float* inp = (const float*)d_in[0];
    const float* tgt = (const float*)d_in[1];
    float* out = (float*)d_out;

    hipMemsetAsync(d_out, 0, sizeof(float), stream);   // d_out re-poisoned each call
    dim3 grid(Wd / TX, Hd / TY, 2 * (Dd / CZ));        // (10,12,8) = 960 blocks
    ncc_main<<<grid, 256, 0, stream>>>(inp, tgt, out);
}

// Round 10
// 163.010 us; speedup vs baseline: 1.4837x; 1.0190x over previous
//
#include <hip/hip_runtime.h>

namespace {

typedef _Float16 half_t;
typedef _Float16 half2_t __attribute__((ext_vector_type(2)));
typedef _Float16 half4_t __attribute__((ext_vector_type(4)));

constexpr int Wd = 160, Hd = 192, Dd = 160;
constexpr int TX = 16, TY = 16, CZ = 80;
constexpr int HW = Hd * Wd;
constexpr int LIVE = CZ + 8;               // 88 slices per block
constexpr float INV_K = 1.0f / 729.0f;
constexpr float INV_TOT = 1.0f / 9830400.0f;   // 2*160*192*160
constexpr int R4 = 17;     // xs4h row stride in half4 units (16 cols + 1 pad)
constexpr int RTH = 68;    // xsTh row stride in half units (x at 4*x)
constexpr int ROWS = 26;   // 24 halo rows + 2 pad rows absorbing lanes 240..255

// ROUND 20 (= R19 resubmitted; R19's bench died on container acquisition,
// not on the kernel -- same infra failure mode as R15, which also passed
// unchanged on resubmit): CZ 40 -> 80 (z-halo amortization) on the R18 base.
// R18 post-mortem: paired y-sum WORKED (94.5 -> 87.2 us profiled, conflicts
// halved, VGPR 80 < 128 cliff, no spill). VALU 48% is now top pipe; no pipe
// saturated; cost is the per-slice serial chain x slice count. Cheapest
// remaining waste: z-halo overhead LIVE/CZ = 48/40 = 1.20x. CZ=80 gives
// 88/80 = 1.10x: total block-slices 46080 -> 42240 (-8.3%), half the
// per-block prologue. Grid (10,12,4) = 480 blocks = 8 XCDs x 60 (swizzle
// rescaled; ~0.9 MB per-XCD working set < 4 MB L2). Loop body untouched
// (18-unroll: 18 = 0 mod 9 and mod 2, so slot/parity carry across trips;
// tail guard s < 88). Registers/LDS identical to R18.
// INVARIANTS: VGPR < 128, WRITE_SIZE ~30 KB, FETCH ~44-47 MB.

__global__ __launch_bounds__(256)
void ncc_main(const float* __restrict__ inp, const float* __restrict__ tgt,
              float* __restrict__ out)
{
    __shared__ half4_t xs4h[2][ROWS * R4];   // 2 x 3536 B
    __shared__ half_t  xsTh[2][ROWS * RTH];  // 2 x 3536 B
    __shared__ half4_t ringAB[9 * 256];      // 18432 B: z-ring {II,IT,TT,I}
    __shared__ half_t  ringT[9 * 256];       //  4608 B: z-ring {T}
    __shared__ float   red[4];

    const int tid = threadIdx.x;

    // ---- XCD-aware remap (R17): 480 blocks = 8 x 60, bijective.
    const int lin = (int)blockIdx.x + 10 * (int)blockIdx.y + 120 * (int)blockIdx.z;
    const int swz = (lin & 7) * 60 + (lin >> 3);
    const int bx = swz % 10;
    const int by = (swz / 10) % 12;
    const int bz = swz / 120;

    const int n  = bz >> 1;
    const int zc = bz & 1;
    const int x0 = bx * TX, y0 = by * TY, z0 = zc * CZ;

    // zero the ring (covers all 256 entries per slot; no sync needed)
    #pragma unroll
    for (int q = 0; q < 9; ++q) {
        ringAB[q * 256 + tid] = (half4_t)0;
        ringT[q * 256 + tid] = (half_t)0.f;
    }

    // ---- phase-1 decode: (row r 0..25) x (half h) x (field f)
    const int f = tid % 5;
    const int j = tid / 5;
    const int r = j >> 1, h = j & 1;
    const int gy = y0 - 4 + r;
    const bool yok = (tid < 240) && (gy >= 0) && (gy < Hd);
    const int gyc = min(max(gy, 0), Hd - 1);
    const int gxb = x0 - 4 + 8 * h;
    const bool uI = (f == 0) || (f == 1) || (f == 3);
    const float bI = (f == 0) ? 1.f : 0.f;
    const float bT = (f == 1 || f == 2) ? 0.5f : 0.f;
    const float bC = (f == 1 || f == 2) ? 0.5f : ((f >= 3) ? 1.f : 0.f);

#define DECODE(c) \
    int voff##c; float aI##c, aTC##c; \
    { const int gx = gxb + 4 * c; \
      const float m = (yok && gx >= 0 && gx < Wd) ? 1.f : 0.f; \
      const int gxc = min(max(gx, 0), Wd - 4); \
      voff##c = gyc * Wd + gxc; \
      aI##c = uI ? m : 0.f; aTC##c = uI ? 0.f : 0.5f * m; }
    DECODE(0) DECODE(1) DECODE(2) DECODE(3)
#undef DECODE

    const int nb = n * (Dd * HW);            // < 2^24, int math is exact
    const float* baseI = inp + nb;           // uniform -> SGPR pair
    const float* baseT = tgt + nb;

    // unified store base (both layouts are stride-4 halves): static imm offsets
    const int stoff = (f < 4) ? ((r * R4) * 4 + 32 * h + f) : (r * RTH + 32 * h);
    half_t* const st0 = (f < 4) ? ((half_t*)xs4h[0] + stoff) : (xsTh[0] + stoff);
    half_t* const st1 = (f < 4) ? ((half_t*)xs4h[1] + stoff) : (xsTh[1] + stoff);

    // ---- phase-2 decode: thread t<128 owns output pair (xi, 2yp),(xi, 2yp+1)
    const int xi = tid & 15;
    const int yp = (tid >> 4) & 7;
    const bool p2on = tid < 128;
    const half4_t* const rd4_0 = &xs4h[0][(2 * yp) * R4 + xi];
    const half4_t* const rd4_1 = &xs4h[1][(2 * yp) * R4 + xi];
    const half_t*  const rdT_0 = &xsTh[0][(2 * yp) * RTH + 4 * xi];
    const half_t*  const rdT_1 = &xsTh[1][(2 * yp) * RTH + 4 * xi];

    float4 S4a = make_float4(0.f, 0.f, 0.f, 0.f);
    float4 S4b = make_float4(0.f, 0.f, 0.f, 0.f);
    float STa = 0.f, STb = 0.f, acc = 0.f;

    // two prefetch sets, roles alternate with static slice parity
#define DECL_SET(S) \
    float4 S##I0, S##I1, S##I2, S##I3, S##T0, S##T1, S##T2, S##T3; \
    S##I0 = S##I1 = S##I2 = S##I3 = make_float4(0.f, 0.f, 0.f, 0.f); \
    S##T0 = S##T1 = S##T2 = S##T3 = S##I0;
    DECL_SET(A) DECL_SET(B)
#undef DECL_SET

#define PRELOAD(S, zz) { \
    const float* pI = baseI + (zz) * HW; \
    const float* pT = baseT + (zz) * HW; \
    S##I0 = *(const float4*)(pI + voff0); S##T0 = *(const float4*)(pT + voff0); \
    S##I1 = *(const float4*)(pI + voff1); S##T1 = *(const float4*)(pT + voff1); \
    S##I2 = *(const float4*)(pI + voff2); S##T2 = *(const float4*)(pT + voff2); \
    S##I3 = *(const float4*)(pI + voff3); S##T3 = *(const float4*)(pT + voff3); }

    // prologue: s=0 -> set A (even), s=1 -> set B (odd)
    if (z0 - 4 >= 0) PRELOAD(A, z0 - 4)
    if (z0 - 3 >= 0) PRELOAD(B, z0 - 3)

#define PRODC(S, c, P0, P1, P2, P3) { \
    P0 = fmaf(S##I##c.x, aI##c, fmaf(S##T##c.x, aTC##c, aTC##c)) * fmaf(S##I##c.x, bI, fmaf(S##T##c.x, bT, bC)); \
    P1 = fmaf(S##I##c.y, aI##c, fmaf(S##T##c.y, aTC##c, aTC##c)) * fmaf(S##I##c.y, bI, fmaf(S##T##c.y, bT, bC)); \
    P2 = fmaf(S##I##c.z, aI##c, fmaf(S##T##c.z, aTC##c, aTC##c)) * fmaf(S##I##c.z, bI, fmaf(S##T##c.z, bT, bC)); \
    P3 = fmaf(S##I##c.w, aI##c, fmaf(S##T##c.w, aTC##c, aTC##c)) * fmaf(S##I##c.w, bI, fmaf(S##T##c.w, bT, bC)); }

    // body for one slice; SET = prefetch set holding slice s, also the
    // target for the s+2 load (same parity)
#define SLICE_BODY(SET) { \
    const int zi = z0 - 4 + s; \
    const bool zok = (zi >= 0) && (zi < Dd);        /* uniform */ \
    const int sl = u % 9;                           /* static */ \
    const int pb = u & 1;                           /* static */ \
    float o0, o1, o2, o3, o4, o5, o6, o7; \
    if (zok) { \
        float p0, p1, p2, p3, p4, p5, p6, p7; \
        float p8, p9, p10, p11, p12, p13, p14, p15; \
        PRODC(SET, 0, p0,  p1,  p2,  p3) \
        PRODC(SET, 1, p4,  p5,  p6,  p7) \
        PRODC(SET, 2, p8,  p9,  p10, p11) \
        PRODC(SET, 3, p12, p13, p14, p15) \
        float ss = p0 + p1 + p2 + p3 + p4 + p5 + p6 + p7 + p8; \
        o0 = ss; \
        ss += p9  - p0; o1 = ss; \
        ss += p10 - p1; o2 = ss; \
        ss += p11 - p2; o3 = ss; \
        ss += p12 - p3; o4 = ss; \
        ss += p13 - p4; o5 = ss; \
        ss += p14 - p5; o6 = ss; \
        ss += p15 - p6; o7 = ss; \
    } \
    {   /* prefetch slice s+2 into the same set (depth-2 pipeline) */ \
        const int zi2 = z0 - 2 + s; \
        if ((s + 2) < LIVE && zi2 >= 0 && zi2 < Dd) PRELOAD(SET, zi2) \
    } \
    if (zok) { \
        half_t* const st = pb ? st1 : st0; \
        st[0]  = (half_t)o0; st[4]  = (half_t)o1; \
        st[8]  = (half_t)o2; st[12] = (half_t)o3; \
        st[16] = (half_t)o4; st[20] = (half_t)o5; \
        st[24] = (half_t)o6; st[28] = (half_t)o7; \
    } \
    __syncthreads();                                /* single barrier */ \
    half2_t a01_0 = (half2_t)0, a23_0 = (half2_t)0; \
    half2_t a01_1 = (half2_t)0, a23_1 = (half2_t)0; \
    half_t aT0 = (half_t)0.f, aT1 = (half_t)0.f; \
    if (zok && p2on) { \
        const half4_t* const rd4 = pb ? rd4_1 : rd4_0; \
        const half_t*  const rdT = pb ? rdT_1 : rdT_0; \
        const half4_t v0 = rd4[0]; \
        const half4_t v9 = rd4[9 * R4]; \
        const half_t t0 = rdT[0]; \
        const half_t t9 = rdT[9 * RTH]; \
        half2_t m01 = (half2_t)0, m23 = (half2_t)0; \
        half_t mT = (half_t)0.f; \
        _Pragma("unroll") \
        for (int k = 1; k < 9; ++k) { \
            const half4_t v = rd4[k * R4]; \
            const half2_t vlo = {v.x, v.y}; \
            const half2_t vhi = {v.z, v.w}; \
            m01 += vlo; m23 += vhi; \
            mT += rdT[k * RTH]; \
        } \
        const half2_t v0lo = {v0.x, v0.y}, v0hi = {v0.z, v0.w}; \
        const half2_t v9lo = {v9.x, v9.y}, v9hi = {v9.z, v9.w}; \
        a01_0 = m01 + v0lo; a23_0 = m23 + v0hi; aT0 = mT + t0; \
        a01_1 = m01 + v9lo; a23_1 = m23 + v9hi; aT1 = mT + t9; \
    } \
    if (p2on) { /* ring shift (zeros when !zok) + accumulate, pair-adjacent */ \
        half4_t* const rAB = &ringAB[sl * 256 + 2 * tid]; \
        half2_t* const rT  = (half2_t*)&ringT[sl * 256 + 2 * tid]; \
        const half4_t oA0 = rAB[0]; \
        const half4_t oA1 = rAB[1]; \
        const half2_t oT  = *rT; \
        S4a.x += (float)a01_0.x - (float)oA0.x; \
        S4a.y += (float)a01_0.y - (float)oA0.y; \
        S4a.z += (float)a23_0.x - (float)oA0.z; \
        S4a.w += (float)a23_0.y - (float)oA0.w; \
        STa   += (float)aT0 - (float)oT.x; \
        S4b.x += (float)a01_1.x - (float)oA1.x; \
        S4b.y += (float)a01_1.y - (float)oA1.y; \
        S4b.z += (float)a23_1.x - (float)oA1.z; \
        S4b.w += (float)a23_1.y - (float)oA1.w; \
        STb   += (float)aT1 - (float)oT.y; \
        const half4_t nA0 = {a01_0.x, a01_0.y, a23_0.x, a23_0.y}; \
        const half4_t nA1 = {a01_1.x, a01_1.y, a23_1.x, a23_1.y}; \
        rAB[0] = nA0; rAB[1] = nA1; \
        const half2_t nT = {aT0, aT1}; \
        *rT = nT; \
    } \
    if (s >= 8 && p2on) {                           /* output z = z0+s-8 */ \
        { const float sii = S4a.x, sit = S4a.y, stt = S4a.z, si = S4a.w, stv = STa; \
          const float cross = sit - si * stv * INV_K; \
          const float tvar  = stt - stv * stv * INV_K; \
          const float ivar  = sii - si  * si  * INV_K; \
          acc += cross * cross * __builtin_amdgcn_rcpf(tvar * ivar + 1e-5f); } \
        { const float sii = S4b.x, sit = S4b.y, stt = S4b.z, si = S4b.w, stv = STb; \
          const float cross = sit - si * stv * INV_K; \
          const float tvar  = stt - stv * stv * INV_K; \
          const float ivar  = sii - si  * si  * INV_K; \
          acc += cross * cross * __builtin_amdgcn_rcpf(tvar * ivar + 1e-5f); } \
    } }

    for (int tb = 0; tb < 90; tb += 18) {          // 88 live; 18-unroll x 5
        #pragma unroll
        for (int u = 0; u < 18; ++u) {
            const int s = tb + u;                  // block-uniform
            if (s < LIVE) {
                if ((u & 1) == 0) SLICE_BODY(A)
                else              SLICE_BODY(B)
            }
        }
    }
#undef SLICE_BODY
#undef PRELOAD
#undef PRODC

    // ---- block reduction + fused finalize (one atomic per block)
    #pragma unroll
    for (int off = 32; off > 0; off >>= 1) acc += __shfl_down(acc, off, 64);
    if ((tid & 63) == 0) red[tid >> 6] = acc;
    __syncthreads();
    if (tid == 0) {
        const float tot = red[0] + red[1] + red[2] + red[3];
        atomicAdd(out, -tot * INV_TOT);
    }
}

} // namespace

extern "C" void kernel_launch(void* const* d_in, const int* in_sizes, int n_in,
                              void* d_out, int out_size, void* d_ws, size_t ws_size,
                              hipStream_t stream)
{
    const float* inp = (const float*)d_in[0];
    const float* tgt = (const float*)d_in[1];
    float* out = (float*)d_out;

    hipMemsetAsync(d_out, 0, sizeof(float), stream);   // d_out re-poisoned each call
    dim3 grid(Wd / TX, Hd / TY, 2 * (Dd / CZ));        // (10,12,4) = 480 blocks
    ncc_main<<<grid, 256, 0, stream>>>(inp, tgt, out);
}

// Round 11
// 160.422 us; speedup vs baseline: 1.5076x; 1.0161x over previous
//
#include <hip/hip_runtime.h>

namespace {

typedef _Float16 half_t;
typedef _Float16 half2_t __attribute__((ext_vector_type(2)));
typedef _Float16 half4_t __attribute__((ext_vector_type(4)));
typedef _Float16 half8_t __attribute__((ext_vector_type(8)));

constexpr int Wd = 160, Hd = 192, Dd = 160;
constexpr int TX = 16, TY = 16, CZ = 80;
constexpr int HW = Hd * Wd;
constexpr int LIVE = CZ + 8;               // 88 slices per block
constexpr float INV_K = 1.0f / 729.0f;
constexpr float INV_TOT = 1.0f / 9830400.0f;   // 2*160*192*160
constexpr int R8 = 17;     // xs8 row stride in half8 units (16 cols + 1 pad)
constexpr int ROWS = 26;   // 24 halo rows + 2 pad rows absorbing lanes 240..255

// ROUND 21: unified half8 field layout on the R20 base (CZ=80).
// R20 post-mortem: CZ=80 bench-best (163 us) but profiled flat (88.2) --
// slice saving offset by residency loss (480 blk = 1.875/CU). Geometry
// tuning closed. R18's win came from cutting phase-2 LDS instructions;
// this round is the remaining cut of that kind: pack all 5 fields into
// ONE half8 {II,IT,TT,I,T,pad3} per (row,col). Phase-2: 1 ds_read_b128
// per row (was b64+b16 = 2 reads) -> 10 reads/thread/slice (was 20);
// ring pair becomes b128 r/w (6 -> 4 ops). Per-thread phase-2 LDS
// 26 -> 14 instrs. LDS bytes identical (2x26x17x16B = old xs4h+xsTh).
// y-sum adds only the 3 meaningful half2s -> VALU unchanged; pad lanes
// never consumed (lane-wise pk adds, stale/NaN is harmless).
// INVARIANTS: VGPR < 128, WRITE_SIZE ~30 KB, FETCH ~42 MB.

__global__ __launch_bounds__(256)
void ncc_main(const float* __restrict__ inp, const float* __restrict__ tgt,
              float* __restrict__ out)
{
    __shared__ half8_t xs8[2][ROWS * R8];    // 2 x 7072 B: {II,IT,TT,I,T,-,-,-}
    __shared__ half4_t ringAB[9 * 256];      // 18432 B: z-ring {II,IT,TT,I}
    __shared__ half_t  ringT[9 * 256];       //  4608 B: z-ring {T}
    __shared__ float   red[4];

    const int tid = threadIdx.x;

    // ---- XCD-aware remap (R17): 480 blocks = 8 x 60, bijective.
    const int lin = (int)blockIdx.x + 10 * (int)blockIdx.y + 120 * (int)blockIdx.z;
    const int swz = (lin & 7) * 60 + (lin >> 3);
    const int bx = swz % 10;
    const int by = (swz / 10) % 12;
    const int bz = swz / 120;

    const int n  = bz >> 1;
    const int zc = bz & 1;
    const int x0 = bx * TX, y0 = by * TY, z0 = zc * CZ;

    // zero the ring (covers all 256 entries per slot; no sync needed)
    #pragma unroll
    for (int q = 0; q < 9; ++q) {
        ringAB[q * 256 + tid] = (half4_t)0;
        ringT[q * 256 + tid] = (half_t)0.f;
    }

    // ---- phase-1 decode: (row r 0..25) x (half h) x (field f)
    const int f = tid % 5;
    const int j = tid / 5;
    const int r = j >> 1, h = j & 1;
    const int gy = y0 - 4 + r;
    const bool yok = (tid < 240) && (gy >= 0) && (gy < Hd);
    const int gyc = min(max(gy, 0), Hd - 1);
    const int gxb = x0 - 4 + 8 * h;
    const bool uI = (f == 0) || (f == 1) || (f == 3);
    const float bI = (f == 0) ? 1.f : 0.f;
    const float bT = (f == 1 || f == 2) ? 0.5f : 0.f;
    const float bC = (f == 1 || f == 2) ? 0.5f : ((f >= 3) ? 1.f : 0.f);

#define DECODE(c) \
    int voff##c; float aI##c, aTC##c; \
    { const int gx = gxb + 4 * c; \
      const float m = (yok && gx >= 0 && gx < Wd) ? 1.f : 0.f; \
      const int gxc = min(max(gx, 0), Wd - 4); \
      voff##c = gyc * Wd + gxc; \
      aI##c = uI ? m : 0.f; aTC##c = uI ? 0.f : 0.5f * m; }
    DECODE(0) DECODE(1) DECODE(2) DECODE(3)
#undef DECODE

    const int nb = n * (Dd * HW);            // < 2^24, int math is exact
    const float* baseI = inp + nb;           // uniform -> SGPR pair
    const float* baseT = tgt + nb;

    // unified store base: column (8h+k) field f at halves (r*R8+8h+k)*8 + f
    const int stoff = (r * R8 + 8 * h) * 8 + f;
    half_t* const st0 = (half_t*)xs8[0] + stoff;
    half_t* const st1 = (half_t*)xs8[1] + stoff;

    // ---- phase-2 decode: thread t<128 owns output pair (xi, 2yp),(xi, 2yp+1)
    const int xi = tid & 15;
    const int yp = (tid >> 4) & 7;
    const bool p2on = tid < 128;
    const half8_t* const rd8_0 = &xs8[0][(2 * yp) * R8 + xi];
    const half8_t* const rd8_1 = &xs8[1][(2 * yp) * R8 + xi];

    float4 S4a = make_float4(0.f, 0.f, 0.f, 0.f);
    float4 S4b = make_float4(0.f, 0.f, 0.f, 0.f);
    float STa = 0.f, STb = 0.f, acc = 0.f;

    // two prefetch sets, roles alternate with static slice parity
#define DECL_SET(S) \
    float4 S##I0, S##I1, S##I2, S##I3, S##T0, S##T1, S##T2, S##T3; \
    S##I0 = S##I1 = S##I2 = S##I3 = make_float4(0.f, 0.f, 0.f, 0.f); \
    S##T0 = S##T1 = S##T2 = S##T3 = S##I0;
    DECL_SET(A) DECL_SET(B)
#undef DECL_SET

#define PRELOAD(S, zz) { \
    const float* pI = baseI + (zz) * HW; \
    const float* pT = baseT + (zz) * HW; \
    S##I0 = *(const float4*)(pI + voff0); S##T0 = *(const float4*)(pT + voff0); \
    S##I1 = *(const float4*)(pI + voff1); S##T1 = *(const float4*)(pT + voff1); \
    S##I2 = *(const float4*)(pI + voff2); S##T2 = *(const float4*)(pT + voff2); \
    S##I3 = *(const float4*)(pI + voff3); S##T3 = *(const float4*)(pT + voff3); }

    // prologue: s=0 -> set A (even), s=1 -> set B (odd)
    if (z0 - 4 >= 0) PRELOAD(A, z0 - 4)
    if (z0 - 3 >= 0) PRELOAD(B, z0 - 3)

#define PRODC(S, c, P0, P1, P2, P3) { \
    P0 = fmaf(S##I##c.x, aI##c, fmaf(S##T##c.x, aTC##c, aTC##c)) * fmaf(S##I##c.x, bI, fmaf(S##T##c.x, bT, bC)); \
    P1 = fmaf(S##I##c.y, aI##c, fmaf(S##T##c.y, aTC##c, aTC##c)) * fmaf(S##I##c.y, bI, fmaf(S##T##c.y, bT, bC)); \
    P2 = fmaf(S##I##c.z, aI##c, fmaf(S##T##c.z, aTC##c, aTC##c)) * fmaf(S##I##c.z, bI, fmaf(S##T##c.z, bT, bC)); \
    P3 = fmaf(S##I##c.w, aI##c, fmaf(S##T##c.w, aTC##c, aTC##c)) * fmaf(S##I##c.w, bI, fmaf(S##T##c.w, bT, bC)); }

    // body for one slice; SET = prefetch set holding slice s, also the
    // target for the s+2 load (same parity)
#define SLICE_BODY(SET) { \
    const int zi = z0 - 4 + s; \
    const bool zok = (zi >= 0) && (zi < Dd);        /* uniform */ \
    const int sl = u % 9;                           /* static */ \
    const int pb = u & 1;                           /* static */ \
    float o0, o1, o2, o3, o4, o5, o6, o7; \
    if (zok) { \
        float p0, p1, p2, p3, p4, p5, p6, p7; \
        float p8, p9, p10, p11, p12, p13, p14, p15; \
        PRODC(SET, 0, p0,  p1,  p2,  p3) \
        PRODC(SET, 1, p4,  p5,  p6,  p7) \
        PRODC(SET, 2, p8,  p9,  p10, p11) \
        PRODC(SET, 3, p12, p13, p14, p15) \
        float ss = p0 + p1 + p2 + p3 + p4 + p5 + p6 + p7 + p8; \
        o0 = ss; \
        ss += p9  - p0; o1 = ss; \
        ss += p10 - p1; o2 = ss; \
        ss += p11 - p2; o3 = ss; \
        ss += p12 - p3; o4 = ss; \
        ss += p13 - p4; o5 = ss; \
        ss += p14 - p5; o6 = ss; \
        ss += p15 - p6; o7 = ss; \
    } \
    {   /* prefetch slice s+2 into the same set (depth-2 pipeline) */ \
        const int zi2 = z0 - 2 + s; \
        if ((s + 2) < LIVE && zi2 >= 0 && zi2 < Dd) PRELOAD(SET, zi2) \
    } \
    if (zok) { \
        half_t* const st = pb ? st1 : st0; \
        st[0]  = (half_t)o0; st[8]  = (half_t)o1; \
        st[16] = (half_t)o2; st[24] = (half_t)o3; \
        st[32] = (half_t)o4; st[40] = (half_t)o5; \
        st[48] = (half_t)o6; st[56] = (half_t)o7; \
    } \
    __syncthreads();                                /* single barrier */ \
    half2_t a01_0 = (half2_t)0, a23_0 = (half2_t)0; \
    half2_t a01_1 = (half2_t)0, a23_1 = (half2_t)0; \
    half_t aT0 = (half_t)0.f, aT1 = (half_t)0.f; \
    if (zok && p2on) { \
        const half8_t* const rd8 = pb ? rd8_1 : rd8_0; \
        const half8_t w0 = rd8[0]; \
        const half8_t w9 = rd8[9 * R8]; \
        half2_t m01 = (half2_t)0, m23 = (half2_t)0, m4 = (half2_t)0; \
        _Pragma("unroll") \
        for (int k = 1; k < 9; ++k) { \
            const half8_t w = rd8[k * R8]; \
            const half2_t* wp = (const half2_t*)&w; \
            m01 += wp[0]; m23 += wp[1]; m4 += wp[2]; \
        } \
        const half2_t* w0p = (const half2_t*)&w0; \
        const half2_t* w9p = (const half2_t*)&w9; \
        a01_0 = m01 + w0p[0]; a23_0 = m23 + w0p[1]; aT0 = m4.x + w0p[2].x; \
        a01_1 = m01 + w9p[0]; a23_1 = m23 + w9p[1]; aT1 = m4.x + w9p[2].x; \
    } \
    if (p2on) { /* ring shift (zeros when !zok) + accumulate, b128 pair */ \
        half8_t* const rAB8 = (half8_t*)&ringAB[sl * 256 + 2 * tid]; \
        half2_t* const rT  = (half2_t*)&ringT[sl * 256 + 2 * tid]; \
        const half8_t oA = *rAB8; \
        const half2_t oT = *rT; \
        S4a.x += (float)a01_0.x - (float)oA[0]; \
        S4a.y += (float)a01_0.y - (float)oA[1]; \
        S4a.z += (float)a23_0.x - (float)oA[2]; \
        S4a.w += (float)a23_0.y - (float)oA[3]; \
        STa   += (float)aT0 - (float)oT.x; \
        S4b.x += (float)a01_1.x - (float)oA[4]; \
        S4b.y += (float)a01_1.y - (float)oA[5]; \
        S4b.z += (float)a23_1.x - (float)oA[6]; \
        S4b.w += (float)a23_1.y - (float)oA[7]; \
        STb   += (float)aT1 - (float)oT.y; \
        const half8_t nA = {a01_0.x, a01_0.y, a23_0.x, a23_0.y, \
                            a01_1.x, a01_1.y, a23_1.x, a23_1.y}; \
        *rAB8 = nA; \
        const half2_t nT = {aT0, aT1}; \
        *rT = nT; \
    } \
    if (s >= 8 && p2on) {                           /* output z = z0+s-8 */ \
        { const float sii = S4a.x, sit = S4a.y, stt = S4a.z, si = S4a.w, stv = STa; \
          const float cross = sit - si * stv * INV_K; \
          const float tvar  = stt - stv * stv * INV_K; \
          const float ivar  = sii - si  * si  * INV_K; \
          acc += cross * cross * __builtin_amdgcn_rcpf(tvar * ivar + 1e-5f); } \
        { const float sii = S4b.x, sit = S4b.y, stt = S4b.z, si = S4b.w, stv = STb; \
          const float cross = sit - si * stv * INV_K; \
          const float tvar  = stt - stv * stv * INV_K; \
          const float ivar  = sii - si  * si  * INV_K; \
          acc += cross * cross * __builtin_amdgcn_rcpf(tvar * ivar + 1e-5f); } \
    } }

    for (int tb = 0; tb < 90; tb += 18) {          // 88 live; 18-unroll x 5
        #pragma unroll
        for (int u = 0; u < 18; ++u) {
            const int s = tb + u;                  // block-uniform
            if (s < LIVE) {
                if ((u & 1) == 0) SLICE_BODY(A)
                else              SLICE_BODY(B)
            }
        }
    }
#undef SLICE_BODY
#undef PRELOAD
#undef PRODC

    // ---- block reduction + fused finalize (one atomic per block)
    #pragma unroll
    for (int off = 32; off > 0; off >>= 1) acc += __shfl_down(acc, off, 64);
    if ((tid & 63) == 0) red[tid >> 6] = acc;
    __syncthreads();
    if (tid == 0) {
        const float tot = red[0] + red[1] + red[2] + red[3];
        atomicAdd(out, -tot * INV_TOT);
    }
}

} // namespace

extern "C" void kernel_launch(void* const* d_in, const int* in_sizes, int n_in,
                              void* d_out, int out_size, void* d_ws, size_t ws_size,
                              hipStream_t stream)
{
    const float* inp = (const float*)d_in[0];
    const float* tgt = (const float*)d_in[1];
    float* out = (float*)d_out;

    hipMemsetAsync(d_out, 0, sizeof(float), stream);   // d_out re-poisoned each call
    dim3 grid(Wd / TX, Hd / TY, 2 * (Dd / CZ));        // (10,12,4) = 480 blocks
    ncc_main<<<grid, 256, 0, stream>>>(inp, tgt, out);
}

// Round 12
// 152.206 us; speedup vs baseline: 1.5890x; 1.0540x over previous
//
#include <hip/hip_runtime.h>

namespace {

typedef _Float16 half_t;
typedef _Float16 half2_t __attribute__((ext_vector_type(2)));
typedef _Float16 half4_t __attribute__((ext_vector_type(4)));
typedef _Float16 half8_t __attribute__((ext_vector_type(8)));

constexpr int Wd = 160, Hd = 192, Dd = 160;
constexpr int TX = 16, TY = 16, CZ = 80;
constexpr int HW = Hd * Wd;
constexpr int LIVE = CZ + 8;               // 88 slices per block
constexpr float INV_K = 1.0f / 729.0f;
constexpr float INV_TOT = 1.0f / 9830400.0f;   // 2*160*192*160
constexpr int R8 = 17;     // xs8 row stride in half8 units (16 cols + 1 pad)
constexpr int ROWS = 24;   // exactly the 16+8 y-halo rows needed

// ROUND 22: producer/consumer wave specialization.
// R17-R21 diagnosis: latency/serial-chain bound -- per slice the SAME waves
// run {PRODC+prefix -> store -> barrier -> ysum -> ring} in sequence
// (~600 cyc), no pipe >50%. This round splits roles: tid 128..223 (96 =
// 24 rows x 4 col-groups) PRODUCE slice k+1 into buf[(k+1)&1] while
// tid 0..127 CONSUME slice k from buf[k&1] -- disjoint buffers, one
// barrier/step, slice time -> max(produce, consume) ~ 350 cyc.
// Producer merges all 5 fields per thread (kills the 5x load/decode
// redundancy; II/IT/TT share Im,T' subexpressions; 12 input cols -> 4
// output windows per field), stores packed b32 pairs + b16 (12 ds ops),
// depth-1 single prefetch set (24 VGPR vs 64; loads are L2-resident per
// R17 so one step of cover suffices). Consumer = R21 verbatim (half8
// single-b128 ysum + pair ring). Same math term-by-term (f32-ulp assoc
// changes only, far below the f16 storage rounding already passing).
// INVARIANTS: VGPR < 128 (R13/R16 cliff), WRITE_SIZE ~30 KB, FETCH ~40 MB.

__global__ __launch_bounds__(256)
void ncc_main(const float* __restrict__ inp, const float* __restrict__ tgt,
              float* __restrict__ out)
{
    __shared__ half8_t xs8[2][ROWS * R8];    // 2 x 6528 B: {II,IT,TT,I,T,-,-,-}
    __shared__ half4_t ringAB[9 * 256];      // 18432 B: z-ring {II,IT,TT,I}
    __shared__ half_t  ringT[9 * 256];       //  4608 B: z-ring {T}
    __shared__ float   red[4];

    const int tid = threadIdx.x;

    // ---- XCD-aware remap (R17): 480 blocks = 8 x 60, bijective.
    const int lin = (int)blockIdx.x + 10 * (int)blockIdx.y + 120 * (int)blockIdx.z;
    const int swz = (lin & 7) * 60 + (lin >> 3);
    const int bx = swz % 10;
    const int by = (swz / 10) % 12;
    const int bz = swz / 120;

    const int n  = bz >> 1;
    const int zc = bz & 1;
    const int x0 = bx * TX, y0 = by * TY, z0 = zc * CZ;

    // zero the ring (all 256 entries per slot; prologue barrier orders it)
    #pragma unroll
    for (int q = 0; q < 9; ++q) {
        ringAB[q * 256 + tid] = (half4_t)0;
        ringT[q * 256 + tid] = (half_t)0.f;
    }

    // ---- producer decode: tid 128..223 -> (row r 0..23) x (h,q col-group)
    const bool isProd = (tid >= 128) && (tid < 224);
    const int up = (tid >= 128) ? (tid - 128) : 0;
    const int r  = (up < 96) ? (up >> 2) : 0;
    const int hq = up & 3;
    const int h  = hq >> 1, qx = hq & 1;
    const int gy = y0 - 4 + r;
    const bool yok = (gy >= 0) && (gy < Hd);
    const int gyc = min(max(gy, 0), Hd - 1);
    const int gxs = x0 - 4 + 8 * h + 4 * qx;   // 12 input cols gxs..gxs+11

#define DECODE(c) \
    int voff##c; float m##c; \
    { const int gx = gxs + 4 * (c); \
      m##c = (yok && gx >= 0 && gx < Wd) ? 1.f : 0.f; \
      const int gxc = min(max(gx, 0), Wd - 4); \
      voff##c = gyc * Wd + gxc; }
    DECODE(0) DECODE(1) DECODE(2)
#undef DECODE

    const int nb = n * (Dd * HW);            // < 2^24, int math is exact
    const float* baseI = inp + nb;           // uniform -> SGPR pair
    const float* baseT = tgt + nb;

    // producer store bases: output cols col0..col0+3, half8 layout
    const int col0 = 8 * h + 4 * qx;
    half_t* const sb0 = (half_t*)xs8[0] + (r * R8 + col0) * 8;
    half_t* const sb1 = (half_t*)xs8[1] + (r * R8 + col0) * 8;

    // ---- consumer decode: tid<128 owns output pair (xi, 2yp),(xi, 2yp+1)
    const int xi = tid & 15;
    const int yp = (tid >> 4) & 7;
    const bool p2on = tid < 128;
    const half8_t* const rd8_0 = &xs8[0][(2 * yp) * R8 + xi];
    const half8_t* const rd8_1 = &xs8[1][(2 * yp) * R8 + xi];

    float4 S4a = make_float4(0.f, 0.f, 0.f, 0.f);
    float4 S4b = make_float4(0.f, 0.f, 0.f, 0.f);
    float STa = 0.f, STb = 0.f, acc = 0.f;

    // single producer prefetch set (depth-1; loads are L2-resident per R17)
    float4 SI0, SI1, SI2, ST0, ST1, ST2;
    SI0 = SI1 = SI2 = ST0 = ST1 = ST2 = make_float4(0.f, 0.f, 0.f, 0.f);

#define PRELOAD(zz) { \
    const float* pI = baseI + (zz) * HW; \
    const float* pT = baseT + (zz) * HW; \
    SI0 = *(const float4*)(pI + voff0); ST0 = *(const float4*)(pT + voff0); \
    SI1 = *(const float4*)(pI + voff1); ST1 = *(const float4*)(pT + voff1); \
    SI2 = *(const float4*)(pI + voff2); ST2 = *(const float4*)(pT + voff2); }

#define F4E(v, e) ((e) == 0 ? (v).x : ((e) == 1 ? (v).y : ((e) == 2 ? (v).z : (v).w)))

    // 9-tap sliding windows (4 outputs from 12 inputs), same fold as before
#define WIN4(PP, W) { \
    float ss = PP[0] + PP[1] + PP[2] + PP[3] + PP[4] + PP[5] + PP[6] + PP[7] + PP[8]; \
    W[0] = ss; ss += PP[9]  - PP[0]; W[1] = ss; \
               ss += PP[10] - PP[1]; W[2] = ss; \
               ss += PP[11] - PP[2]; W[3] = ss; }

    // compute + store one slice's x-windows (all 5 fields) to SBP
#define PRODUCE(SBP) { \
    float Im[12], Tr[12], p[12]; \
    float wII[4], wIT[4], wTT[4], wI[4], wT[4]; \
    _Pragma("unroll") \
    for (int e = 0; e < 4; ++e) { \
        Im[e]     = F4E(SI0, e) * m0;  Tr[e]     = fmaf(F4E(ST0, e), 0.5f, 0.5f); \
        Im[4 + e] = F4E(SI1, e) * m1;  Tr[4 + e] = fmaf(F4E(ST1, e), 0.5f, 0.5f); \
        Im[8 + e] = F4E(SI2, e) * m2;  Tr[8 + e] = fmaf(F4E(ST2, e), 0.5f, 0.5f); } \
    _Pragma("unroll") \
    for (int i = 0; i < 12; ++i) \
        p[i] = Im[i] * F4E((i < 4 ? SI0 : (i < 8 ? SI1 : SI2)), i & 3); \
    WIN4(p, wII) \
    _Pragma("unroll") \
    for (int i = 0; i < 12; ++i) p[i] = Im[i] * Tr[i]; \
    WIN4(p, wIT) \
    WIN4(Im, wI) \
    _Pragma("unroll") \
    for (int i = 0; i < 12; ++i) Im[i] = Tr[i] * (i < 4 ? m0 : (i < 8 ? m1 : m2)); \
    _Pragma("unroll") \
    for (int i = 0; i < 12; ++i) p[i] = Im[i] * Tr[i]; \
    WIN4(p, wTT) \
    WIN4(Im, wT) \
    _Pragma("unroll") \
    for (int cc = 0; cc < 4; ++cc) { \
        const half2_t v01 = {(half_t)wII[cc], (half_t)wIT[cc]}; \
        const half2_t v23 = {(half_t)wTT[cc], (half_t)wI[cc]}; \
        ((half2_t*)(SBP))[cc * 4]     = v01; \
        ((half2_t*)(SBP))[cc * 4 + 1] = v23; \
        (SBP)[cc * 8 + 4] = (half_t)wT[cc]; } }

    // ---- prologue: produce slice 0 into buf0; preload slice 1
    if (isProd) {
        if (z0 - 4 >= 0) { PRELOAD(z0 - 4) PRODUCE(sb0) }
        if (z0 - 3 >= 0) PRELOAD(z0 - 3)
    }
    __syncthreads();

    // one step: producer makes slice k+1, consumer eats slice k; 1 barrier
#define STEP_BODY(UU) { \
    const int k = tb + (UU); \
    if (isProd) { \
        const int zi1 = z0 - 3 + k;             /* z of slice k+1 */ \
        if ((k + 1) < LIVE && zi1 >= 0 && zi1 < Dd) { \
            if (((UU) & 1) == 0) PRODUCE(sb1) else PRODUCE(sb0) \
        } \
        const int zi2 = z0 - 2 + k;             /* z of slice k+2 */ \
        if ((k + 2) < LIVE && zi2 >= 0 && zi2 < Dd) PRELOAD(zi2) \
    } \
    { /* consumer: slice k from buf[k&1] */ \
        const int zi = z0 - 4 + k; \
        const bool zok = (zi >= 0) && (zi < Dd); \
        half2_t a01_0 = (half2_t)0, a23_0 = (half2_t)0; \
        half2_t a01_1 = (half2_t)0, a23_1 = (half2_t)0; \
        half_t aT0 = (half_t)0.f, aT1 = (half_t)0.f; \
        if (zok && p2on) { \
            const half8_t* const rd8 = (((UU) & 1) != 0) ? rd8_1 : rd8_0; \
            const half8_t w0 = rd8[0]; \
            const half8_t w9 = rd8[9 * R8]; \
            half2_t m01 = (half2_t)0, m23 = (half2_t)0, m4 = (half2_t)0; \
            _Pragma("unroll") \
            for (int kk = 1; kk < 9; ++kk) { \
                const half8_t w = rd8[kk * R8]; \
                const half2_t* wp = (const half2_t*)&w; \
                m01 += wp[0]; m23 += wp[1]; m4 += wp[2]; \
            } \
            const half2_t* w0p = (const half2_t*)&w0; \
            const half2_t* w9p = (const half2_t*)&w9; \
            a01_0 = m01 + w0p[0]; a23_0 = m23 + w0p[1]; aT0 = m4.x + w0p[2].x; \
            a01_1 = m01 + w9p[0]; a23_1 = m23 + w9p[1]; aT1 = m4.x + w9p[2].x; \
        } \
        if (p2on) { \
            const int sl = (UU) % 9;            /* static */ \
            half8_t* const rAB8 = (half8_t*)&ringAB[sl * 256 + 2 * tid]; \
            half2_t* const rT  = (half2_t*)&ringT[sl * 256 + 2 * tid]; \
            const half8_t oA = *rAB8; \
            const half2_t oT = *rT; \
            S4a.x += (float)a01_0.x - (float)oA[0]; \
            S4a.y += (float)a01_0.y - (float)oA[1]; \
            S4a.z += (float)a23_0.x - (float)oA[2]; \
            S4a.w += (float)a23_0.y - (float)oA[3]; \
            STa   += (float)aT0 - (float)oT.x; \
            S4b.x += (float)a01_1.x - (float)oA[4]; \
            S4b.y += (float)a01_1.y - (float)oA[5]; \
            S4b.z += (float)a23_1.x - (float)oA[6]; \
            S4b.w += (float)a23_1.y - (float)oA[7]; \
            STb   += (float)aT1 - (float)oT.y; \
            const half8_t nA = {a01_0.x, a01_0.y, a23_0.x, a23_0.y, \
                                a01_1.x, a01_1.y, a23_1.x, a23_1.y}; \
            *rAB8 = nA; \
            const half2_t nT = {aT0, aT1}; \
            *rT = nT; \
        } \
        if (k >= 8 && p2on) {                   /* output z = z0+k-8 */ \
            { const float sii = S4a.x, sit = S4a.y, stt = S4a.z, si = S4a.w, stv = STa; \
              const float cross = sit - si * stv * INV_K; \
              const float tvar  = stt - stv * stv * INV_K; \
              const float ivar  = sii - si  * si  * INV_K; \
              acc += cross * cross * __builtin_amdgcn_rcpf(tvar * ivar + 1e-5f); } \
            { const float sii = S4b.x, sit = S4b.y, stt = S4b.z, si = S4b.w, stv = STb; \
              const float cross = sit - si * stv * INV_K; \
              const float tvar  = stt - stv * stv * INV_K; \
              const float ivar  = sii - si  * si  * INV_K; \
              acc += cross * cross * __builtin_amdgcn_rcpf(tvar * ivar + 1e-5f); } \
        } \
    } \
    __syncthreads(); }

    for (int tb = 0; tb < 90; tb += 18) {          // 88 live; 18-unroll x 5
        #pragma unroll
        for (int uu = 0; uu < 18; ++uu) {
            if (tb + uu < LIVE) STEP_BODY(uu)
        }
    }
#undef STEP_BODY
#undef PRODUCE
#undef WIN4
#undef F4E
#undef PRELOAD

    // ---- block reduction + fused finalize (one atomic per block)
    #pragma unroll
    for (int off = 32; off > 0; off >>= 1) acc += __shfl_down(acc, off, 64);
    if ((tid & 63) == 0) red[tid >> 6] = acc;
    __syncthreads();
    if (tid == 0) {
        const float tot = red[0] + red[1] + red[2] + red[3];
        atomicAdd(out, -tot * INV_TOT);
    }
}

} // namespace

extern "C" void kernel_launch(void* const* d_in, const int* in_sizes, int n_in,
                              void* d_out, int out_size, void* d_ws, size_t ws_size,
                              hipStream_t stream)
{
    const float* inp = (const float*)d_in[0];
    const float* tgt = (const float*)d_in[1];
    float* out = (float*)d_out;

    hipMemsetAsync(d_out, 0, sizeof(float), stream);   // d_out re-poisoned each call
    dim3 grid(Wd / TX, Hd / TY, 2 * (Dd / CZ));        // (10,12,4) = 480 blocks
    ncc_main<<<grid, 256, 0, stream>>>(inp, tgt, out);
}